// Round 5
// baseline (818.069 us; speedup 1.0000x reference)
//
#include <hip/hip_runtime.h>
#include <math.h>

typedef _Float16 hlf4 __attribute__((ext_vector_type(4)));
typedef _Float16 hlf8 __attribute__((ext_vector_type(8)));
typedef float f32x4 __attribute__((ext_vector_type(4)));

// async global->LDS, 16B per lane; lds base must be wave-uniform
static __device__ __forceinline__ void gl_lds16(const void* g, void* l) {
    __builtin_amdgcn_global_load_lds(
        (const __attribute__((address_space(1))) unsigned int*)g,
        (__attribute__((address_space(3))) unsigned int*)l, 16, 0, 0);
}

// ---------------- block reductions (deterministic tree order) ----------------
static __device__ __forceinline__ float blk_sum(float v) {
    __shared__ float sm[256];
    int tid = threadIdx.x;
    sm[tid] = v; __syncthreads();
#pragma unroll
    for (int s = 128; s > 0; s >>= 1) {
        if (tid < s) sm[tid] += sm[tid + s];
        __syncthreads();
    }
    float r = sm[0]; __syncthreads();
    return r;
}

static __device__ __forceinline__ float blk_max(float v) {
    __shared__ float sm[256];
    int tid = threadIdx.x;
    sm[tid] = v; __syncthreads();
#pragma unroll
    for (int s = 128; s > 0; s >>= 1) {
        if (tid < s) sm[tid] = fmaxf(sm[tid], sm[tid + s]);
        __syncthreads();
    }
    float r = sm[0]; __syncthreads();
    return r;
}

// ---------------- C normalizer: per-row norms of gathered rows ----------------
__global__ __launch_bounds__(256) void k_row_norms(
    const float* __restrict__ X, const int* __restrict__ idx,
    float* __restrict__ norms, int n) {
    long long r = idx[blockIdx.x];
    const float* xr = X + r * (long long)n;
    float s = 0.f;
    for (int k = threadIdx.x * 4; k < n; k += 256 * 4) {
        float4 v = *(const float4*)(xr + k);
        s = fmaf(v.x, v.x, s); s = fmaf(v.y, v.y, s);
        s = fmaf(v.z, v.z, s); s = fmaf(v.w, v.w, s);
    }
    float tot = blk_sum(s);
    if (threadIdx.x == 0) norms[blockIdx.x] = sqrtf(tot);
}

__global__ __launch_bounds__(256) void k_cinv(
    const float* __restrict__ norms, int m, int n, float* __restrict__ cinv) {
    float s = 0.f;
    for (int i = threadIdx.x; i < m; i += 256) s += norms[i];
    float tot = blk_sum(s);
    if (threadIdx.x == 0) cinv[0] = (float)m * sqrtf((float)n) / tot;  // 1/C
}

// ---------------- xs = x * (1/C): f32 out + f16 copy ----------------
__global__ __launch_bounds__(256) void k_scale2(
    const float* __restrict__ x, const float* __restrict__ cinv,
    float* __restrict__ y, _Float16* __restrict__ yh, long long total4) {
    float c = cinv[0];
    long long i = blockIdx.x * 256ll + threadIdx.x;
    long long stride = (long long)gridDim.x * 256ll;
    for (; i < total4; i += stride) {
        float4 v = ((const float4*)x)[i];
        v.x *= c; v.y *= c; v.z *= c; v.w *= c;
        ((float4*)y)[i] = v;
        hlf4 o = {(_Float16)v.x, (_Float16)v.y, (_Float16)v.z, (_Float16)v.w};
        ((hlf4*)yh)[i] = o;
    }
}

// ---------------- gather + scale + cvt: Xc_h[r] = f16(X[idx[r]] * cinv) ------
__global__ __launch_bounds__(256) void k_gather_cvt(
    const float* __restrict__ X, const int* __restrict__ idx,
    const float* __restrict__ cinv, _Float16* __restrict__ out, int n) {
    long long r = idx[blockIdx.x];
    float c = cinv[0];
    const float* src = X + r * (long long)n;
    _Float16* dst = out + (long long)blockIdx.x * n;
    for (int k = threadIdx.x * 4; k < n; k += 256 * 4) {
        float4 v = *(const float4*)(src + k);
        hlf4 o = {(_Float16)(v.x * c), (_Float16)(v.y * c),
                  (_Float16)(v.z * c), (_Float16)(v.w * c)};
        *(hlf4*)(dst + k) = o;
    }
}

// ---------------- flat f32 -> f16 ----------------
__global__ __launch_bounds__(256) void k_cvt(
    const float* __restrict__ in, _Float16* __restrict__ out, long long n4) {
    long long i = blockIdx.x * 256ll + threadIdx.x;
    long long stride = (long long)gridDim.x * 256ll;
    for (; i < n4; i += stride) {
        float4 v = ((const float4*)in)[i];
        hlf4 o = {(_Float16)v.x, (_Float16)v.y, (_Float16)v.z, (_Float16)v.w};
        ((hlf4*)out)[i] = o;
    }
}

// ---------------- transpose + cvt: in[R][Cc] f32 -> out[Cc][R] f16 ----------
__global__ __launch_bounds__(256) void k_tcvt(
    const float* __restrict__ in, _Float16* __restrict__ out, int R, int Cc) {
    __shared__ _Float16 t[32][34];
    int tx = threadIdx.x & 31, ty = threadIdx.x >> 5;   // ty 0..7
    int c0 = blockIdx.x * 32, r0 = blockIdx.y * 32;
#pragma unroll
    for (int i = 0; i < 32; i += 8)
        t[ty + i][tx] = (_Float16)in[(long long)(r0 + ty + i) * Cc + c0 + tx];
    __syncthreads();
#pragma unroll
    for (int i = 0; i < 32; i += 8)
        out[(long long)(c0 + ty + i) * R + r0 + tx] = t[tx][ty + i];
}

// ============ barrier-free per-wave-pipelined MFMA NT GEMM (f16) ============
// C[i][j] = sum_k A[i][k]*B[j][k].  128x128 tile, BK=32, 256 thr / 4 waves
// (2Mx2N, 64x64 each, 4x4 frags of 16x16x32). Each wave owns PRIVATE A/B LDS
// slabs (64x32 h, double-buffered; 64 KB/block) staged via global_load_lds
// (wave-scoped). No s_barrier anywhere: the wave syncs on its own counted
// s_waitcnt vmcnt(8) -> next tile's 8 loads stay in flight through the MFMA
// phase (T4, per-wave; vmcnt semantics per m135). Both-sides XOR seg-swizzle
// (rule 21): global seg = physseg ^ (row&3); frag read applies same XOR ->
// minimum bank aliasing. XCD-bijective block remap (T1; launches keep nwg%8==0).
// gridDim.z>1: K split; f32 partial written to part + z*zstride.
__global__ __launch_bounds__(256) void k_gemmw(
    const _Float16* __restrict__ A, int lda,
    const _Float16* __restrict__ B, int ldb,
    float* __restrict__ Cc, long long ldc, int K,
    float* __restrict__ part, long long zstride) {
    __shared__ _Float16 lds[4][2][2][2048];   // [wave][buf][A/B][64*32]
    const int tid = threadIdx.x, lane = tid & 63, wv = tid >> 6;

    // XCD-aware bijective remap of linearized block id (nwg % 8 == 0)
    const int gx = gridDim.x, gy = gridDim.y;
    int lin = blockIdx.x + gx * (blockIdx.y + gy * blockIdx.z);
    const int cpx = (gx * gy * (int)gridDim.z) >> 3;
    lin = (lin & 7) * cpx + (lin >> 3);
    const int bx = lin % gx; const int rest = lin / gx;
    const int by = rest % gy, bz = rest / gy;

    const long long m0 = (long long)bx * 128;
    const long long n0 = (long long)by * 128;
    const int KC = K / gridDim.z;
    const int kbase = bz * KC;
    const int wm = (wv >> 1) * 64, wn = (wv & 1) * 64;
    const int fr = lane & 15, fq = lane >> 4;

    // per-wave staging: 4 groups/matrix; slot s=g*64+lane -> row s>>2, seg s&3
    const _Float16* Ag[4];
    const _Float16* Bg[4];
#pragma unroll
    for (int g = 0; g < 4; ++g) {
        const int s = g * 64 + lane;
        const int row = s >> 2;
        const int gofs = (((s & 3) ^ (row & 3)) << 3);   // halfs
        Ag[g] = A + (m0 + wm + row) * (long long)lda + kbase + gofs;
        Bg[g] = B + (n0 + wn + row) * (long long)ldb + kbase + gofs;
    }

    f32x4 acc[4][4] = {};

#define STAGE(bufi, kt)                                                    \
    {                                                                      \
        const long long ko_ = (long long)(kt) * 32;                        \
        _Float16* la_ = &lds[wv][bufi][0][0];                              \
        _Float16* lb_ = &lds[wv][bufi][1][0];                              \
        gl_lds16(Ag[0] + ko_, la_ + 0);    gl_lds16(Bg[0] + ko_, lb_ + 0); \
        gl_lds16(Ag[1] + ko_, la_ + 512);  gl_lds16(Bg[1] + ko_, lb_ + 512); \
        gl_lds16(Ag[2] + ko_, la_ + 1024); gl_lds16(Bg[2] + ko_, lb_ + 1024); \
        gl_lds16(Ag[3] + ko_, la_ + 1536); gl_lds16(Bg[3] + ko_, lb_ + 1536); \
    }

    const int NT = KC / 32;
    STAGE(0, 0);
    int buf = 0;
    for (int kt = 0; kt < NT; ++kt) {
        if (kt + 1 < NT) {
            STAGE(buf ^ 1, kt + 1);
            asm volatile("s_waitcnt vmcnt(8)" ::: "memory");   // prev 8 landed
        } else {
            asm volatile("s_waitcnt vmcnt(0)" ::: "memory");
        }
        __builtin_amdgcn_sched_barrier(0);
        hlf8 af[4], bf[4];
        const int swf = (fq ^ (fr & 3)) << 3;
#pragma unroll
        for (int i = 0; i < 4; ++i)
            af[i] = *(const hlf8*)&lds[wv][buf][0][(i * 16 + fr) * 32 + swf];
#pragma unroll
        for (int j = 0; j < 4; ++j)
            bf[j] = *(const hlf8*)&lds[wv][buf][1][(j * 16 + fr) * 32 + swf];
#pragma unroll
        for (int i = 0; i < 4; ++i)
#pragma unroll
            for (int j = 0; j < 4; ++j)
                acc[i][j] = __builtin_amdgcn_mfma_f32_16x16x32_f16(af[i], bf[j], acc[i][j], 0, 0, 0);
        buf ^= 1;
    }
#undef STAGE

    float* outp = (gridDim.z == 1) ? Cc : (part + (long long)bz * zstride);
    // C/D layout: col=lane&15, row=(lane>>4)*4+reg (m89-verified)
#pragma unroll
    for (int i = 0; i < 4; ++i)
#pragma unroll
        for (int j = 0; j < 4; ++j) {
            float* cp = outp + (m0 + wm + i * 16 + fq * 4) * ldc + (n0 + wn + j * 16 + fr);
#pragma unroll
            for (int r = 0; r < 4; ++r) cp[(long long)r * ldc] = acc[i][j][r];
        }
}

// ---------------- fallback reg-staged GEMM (f32 A), 8-wave ------------------
#define GLDH 40
template <typename TA>
static __device__ __forceinline__ hlf8 ld8f(const TA* p) {
    if constexpr (sizeof(TA) == 4) {
        float4 a = *(const float4*)(p + 0);
        float4 b = *(const float4*)(p + 4);
        hlf8 r = {(_Float16)a.x, (_Float16)a.y, (_Float16)a.z, (_Float16)a.w,
                  (_Float16)b.x, (_Float16)b.y, (_Float16)b.z, (_Float16)b.w};
        return r;
    } else {
        return *(const hlf8*)p;
    }
}

template <typename TA>
__global__ __launch_bounds__(512) void k_gemm8(
    const TA* __restrict__ A, int lda,
    const _Float16* __restrict__ B, int ldb,
    float* __restrict__ Cc, long long ldc, int K,
    float* __restrict__ part, long long zstride) {
    __shared__ _Float16 Ah[2][128 * GLDH];
    __shared__ _Float16 Bh[2][128 * GLDH];
    const int tid = threadIdx.x;
    const long long m0 = (long long)blockIdx.x * 128;
    const long long n0 = (long long)blockIdx.y * 128;
    const int KC = K / gridDim.z;
    const int kbase = blockIdx.z * KC;
    const int srow = tid >> 2, sseg = tid & 3;
    const TA* Ap = A + (m0 + srow) * (long long)lda + kbase + sseg * 8;
    const _Float16* Bp = B + (n0 + srow) * (long long)ldb + kbase + sseg * 8;
    const int lane = tid & 63, wv = tid >> 6;
    const int wm = (wv >> 2) * 64, wn = (wv & 3) * 32;
    const int fr = lane & 15, fq = lane >> 4;
    const int sOff = srow * GLDH + sseg * 8;

    f32x4 acc[4][2] = {};
    hlf8 ra, rb;
    ra = ld8f(Ap); rb = ld8f(Bp);
    *(hlf8*)&Ah[0][sOff] = ra; *(hlf8*)&Bh[0][sOff] = rb;
    __syncthreads();

    const int NT = KC / 32;
    for (int kt = 0; kt < NT; ++kt) {
        const int cur = kt & 1;
        if (kt + 1 < NT) {
            ra = ld8f(Ap + (long long)(kt + 1) * 32);
            rb = ld8f(Bp + (long long)(kt + 1) * 32);
        }
        hlf8 af[4], bf[2];
#pragma unroll
        for (int i = 0; i < 4; ++i)
            af[i] = *(const hlf8*)&Ah[cur][(wm + i * 16 + fr) * GLDH + fq * 8];
#pragma unroll
        for (int j = 0; j < 2; ++j)
            bf[j] = *(const hlf8*)&Bh[cur][(wn + j * 16 + fr) * GLDH + fq * 8];
#pragma unroll
        for (int i = 0; i < 4; ++i)
#pragma unroll
            for (int j = 0; j < 2; ++j)
                acc[i][j] = __builtin_amdgcn_mfma_f32_16x16x32_f16(af[i], bf[j], acc[i][j], 0, 0, 0);
        if (kt + 1 < NT) {
            const int nx = cur ^ 1;
            *(hlf8*)&Ah[nx][sOff] = ra; *(hlf8*)&Bh[nx][sOff] = rb;
        }
        __syncthreads();
    }

    float* outp = (gridDim.z == 1) ? Cc : (part + (long long)blockIdx.z * zstride);
#pragma unroll
    for (int i = 0; i < 4; ++i)
#pragma unroll
        for (int j = 0; j < 2; ++j) {
            float* cp = outp + (m0 + wm + i * 16 + fq * 4) * ldc + (n0 + wn + j * 16 + fr);
#pragma unroll
            for (int r = 0; r < 4; ++r) cp[(long long)r * ldc] = acc[i][j][r];
        }
}

// ---------------- split-K reduction: out = sum_z part[z] ----------------
__global__ __launch_bounds__(256) void k_redux(
    const float* __restrict__ part, float* __restrict__ out,
    long long n4, long long zs4, int Z) {
    long long i = blockIdx.x * 256ll + threadIdx.x;
    long long stride = (long long)gridDim.x * 256ll;
    for (; i < n4; i += stride) {
        float4 s = ((const float4*)part)[i];
        for (int z = 1; z < Z; ++z) {
            float4 t = ((const float4*)part)[i + z * zs4];
            s.x += t.x; s.y += t.y; s.z += t.z; s.w += t.w;
        }
        ((float4*)out)[i] = s;
    }
}

// ---------------- row LayerNorm in-place, width W = CNT*256 ----------------
template <int CNT>
__global__ __launch_bounds__(256) void k_layernorm(
    float* __restrict__ Y, const float* __restrict__ g,
    const float* __restrict__ b, int W) {
    float* yr = Y + (long long)blockIdx.x * W;
    float v[CNT];
    float s = 0.f;
#pragma unroll
    for (int i = 0; i < CNT; ++i) {
        v[i] = yr[threadIdx.x + (i << 8)];
        s += v[i];
    }
    float mu = blk_sum(s) / (float)W;
    float sq = 0.f;
#pragma unroll
    for (int i = 0; i < CNT; ++i) {
        float d = v[i] - mu;
        sq = fmaf(d, d, sq);
    }
    float var = blk_sum(sq) / (float)W;
    float rs = rsqrtf(var + 1e-5f);
#pragma unroll
    for (int i = 0; i < CNT; ++i) {
        int col = threadIdx.x + (i << 8);
        yr[col] = (v[i] - mu) * rs * g[col] + b[col];
    }
}

// -------- row softmax in-place, W = 16384; optional f16 copy of result ------
__global__ __launch_bounds__(256) void k_softmax(
    float* __restrict__ S, _Float16* __restrict__ Sh, float scale) {
    float* sr = S + (long long)blockIdx.x * 16384;
    _Float16* shr = Sh ? Sh + (long long)blockIdx.x * 16384 : nullptr;
    float4 r[16];
    float mx = -1e30f;
#pragma unroll
    for (int i = 0; i < 16; ++i) {
        float4 t = ((const float4*)sr)[threadIdx.x + (i << 8)];
        t.x *= scale; t.y *= scale; t.z *= scale; t.w *= scale;
        r[i] = t;
        mx = fmaxf(mx, fmaxf(fmaxf(t.x, t.y), fmaxf(t.z, t.w)));
    }
    mx = blk_max(mx);
    float sum = 0.f;
#pragma unroll
    for (int i = 0; i < 16; ++i) {
        float4 t = r[i];
        t.x = __expf(t.x - mx); t.y = __expf(t.y - mx);
        t.z = __expf(t.z - mx); t.w = __expf(t.w - mx);
        r[i] = t;
        sum += t.x + t.y + t.z + t.w;
    }
    sum = blk_sum(sum);
    float inv = 1.0f / sum;
#pragma unroll
    for (int i = 0; i < 16; ++i) {
        float4 t = r[i];
        t.x *= inv; t.y *= inv; t.z *= inv; t.w *= inv;
        ((float4*)sr)[threadIdx.x + (i << 8)] = t;
        if (shr) {
            hlf4 o = {(_Float16)t.x, (_Float16)t.y, (_Float16)t.z, (_Float16)t.w};
            ((hlf4*)shr)[threadIdx.x + (i << 8)] = o;
        }
    }
}

extern "C" void kernel_launch(void* const* d_in, const int* in_sizes, int n_in,
                              void* d_out, int out_size, void* d_ws, size_t ws_size,
                              hipStream_t stream) {
    const float* x      = (const float*)d_in[0];
    const float* X_data = (const float*)d_in[1];
    const int*   midx   = (const int*)d_in[2];
    const float* W_q    = (const float*)d_in[3];
    const float* W_k    = (const float*)d_in[4];
    const float* W_v    = (const float*)d_in[5];
    const float* g_q    = (const float*)d_in[6];
    const float* b_q    = (const float*)d_in[7];
    const float* g_k    = (const float*)d_in[8];
    const float* b_k    = (const float*)d_in[9];
    const float* g_v    = (const float*)d_in[10];
    const float* b_v    = (const float*)d_in[11];

    const int n  = in_sizes[10];        // 1024
    const int a  = in_sizes[6];         // 256
    const int m  = in_sizes[2];         // 16384
    const int Bn = in_sizes[0] / n;     // 4096

    // output layout: xs | x_hat | attn | v
    float* out  = (float*)d_out;
    float* xs   = out;
    float* xhat = xs + (long long)Bn * n;
    float* attn = xhat + (long long)Bn * n;
    float* vout = attn + (long long)Bn * m;

    // workspace carving (256B aligned). [qmat .. k_h] (~73 MB) is dead before
    // the x_hat GEMM, so the 64 MB split-K partial buffer aliases it.
    char* wp = (char*)d_ws;
    auto carve = [&](size_t bytes) -> char* {
        char* r = wp; wp += (bytes + 255) & ~(size_t)255; return r;
    };
    float*     norms = (float*)carve((size_t)m * 4);
    float*     cinv  = (float*)carve(16);
    char*      alias0 = wp;
    float*     qmat  = (float*)carve((size_t)Bn * a * 4);
    float*     kmat  = (float*)carve((size_t)m * a * 4);
    _Float16*  xs_h  = (_Float16*)carve((size_t)Bn * n * 2);
    _Float16*  Xc_h  = (_Float16*)carve((size_t)m * n * 2);
    _Float16*  Wq_h  = (_Float16*)carve((size_t)a * n * 2);
    _Float16*  Wk_h  = (_Float16*)carve((size_t)a * n * 2);
    _Float16*  Wv_h  = (_Float16*)carve((size_t)n * n * 2);
    _Float16*  q_h   = (_Float16*)carve((size_t)Bn * a * 2);
    _Float16*  k_h   = (_Float16*)carve((size_t)m * a * 2);
    float*     splitk = (float*)alias0;
    const int  SK = 4;                                    // SK*Bn*n*4 = 64MB <= 73MB
    _Float16*  vT_h  = (_Float16*)carve((size_t)n * m * 2);
    size_t used = (size_t)(wp - (char*)d_ws);
    _Float16* attn_h = nullptr;
    if (ws_size >= used + (size_t)Bn * m * 2 + 256)
        attn_h = (_Float16*)carve((size_t)Bn * m * 2);

    // 1) C normalizer
    hipLaunchKernelGGL(k_row_norms, dim3(m), dim3(256), 0, stream, X_data, midx, norms, n);
    hipLaunchKernelGGL(k_cinv, dim3(1), dim3(256), 0, stream, norms, m, n, cinv);

    // 2) xs = x/C (f32 + f16); gathered+scaled Xc in f16
    hipLaunchKernelGGL(k_scale2, dim3(2048), dim3(256), 0, stream,
                       x, cinv, xs, xs_h, (long long)Bn * n / 4);
    hipLaunchKernelGGL(k_gather_cvt, dim3(m), dim3(256), 0, stream,
                       X_data, midx, cinv, Xc_h, n);

    // 3) weights -> f16
    hipLaunchKernelGGL(k_cvt, dim3(256), dim3(256), 0, stream, W_q, Wq_h, (long long)a * n / 4);
    hipLaunchKernelGGL(k_cvt, dim3(256), dim3(256), 0, stream, W_k, Wk_h, (long long)a * n / 4);
    hipLaunchKernelGGL(k_cvt, dim3(1024), dim3(256), 0, stream, W_v, Wv_h, (long long)n * n / 4);

    // 4) projections (barrier-free per-wave MFMA)
    hipLaunchKernelGGL(k_gemmw, dim3(Bn / 128, a / 128), dim3(256), 0, stream,
                       xs_h, n, Wq_h, n, qmat, a, n, (float*)nullptr, 0ll);
    hipLaunchKernelGGL(k_gemmw, dim3(m / 128, a / 128), dim3(256), 0, stream,
                       Xc_h, n, Wk_h, n, kmat, a, n, (float*)nullptr, 0ll);
    hipLaunchKernelGGL(k_gemmw, dim3(m / 128, n / 128), dim3(256), 0, stream,
                       Xc_h, n, Wv_h, n, vout, n, n, (float*)nullptr, 0ll);

    // 5) LayerNorms (f32) + f16 copies of q,k and transposed v
    hipLaunchKernelGGL(k_layernorm<1>, dim3(Bn), dim3(256), 0, stream, qmat, g_q, b_q, a);
    hipLaunchKernelGGL(k_layernorm<1>, dim3(m),  dim3(256), 0, stream, kmat, g_k, b_k, a);
    hipLaunchKernelGGL(k_layernorm<4>, dim3(m),  dim3(256), 0, stream, vout, g_v, b_v, n);
    hipLaunchKernelGGL(k_cvt, dim3(1024), dim3(256), 0, stream, qmat, q_h, (long long)Bn * a / 4);
    hipLaunchKernelGGL(k_cvt, dim3(4096), dim3(256), 0, stream, kmat, k_h, (long long)m * a / 4);
    hipLaunchKernelGGL(k_tcvt, dim3(n / 32, m / 32), dim3(256), 0, stream, vout, vT_h, m, n);

    // 6) S = q k^T (f32 logits), softmax in place (+f16 copy)
    hipLaunchKernelGGL(k_gemmw, dim3(Bn / 128, m / 128), dim3(256), 0, stream,
                       q_h, a, k_h, a, attn, m, a, (float*)nullptr, 0ll);
    float sc = 1.0f / sqrtf((float)a);
    hipLaunchKernelGGL(k_softmax, dim3(Bn), dim3(256), 0, stream, attn, attn_h, sc);

    // 7) x_hat = attn @ v, split-K=4 into aliased partials, then reduce
    long long zstride = (long long)Bn * n;
    if (attn_h) {
        hipLaunchKernelGGL(k_gemmw, dim3(Bn / 128, n / 128, SK), dim3(256), 0, stream,
                           attn_h, m, vT_h, m, xhat, n, m, splitk, zstride);
    } else {
        hipLaunchKernelGGL((k_gemm8<float>), dim3(Bn / 128, n / 128, SK), dim3(512), 0, stream,
                           attn, m, vT_h, m, xhat, n, m, splitk, zstride);
    }
    hipLaunchKernelGGL(k_redux, dim3(2048), dim3(256), 0, stream,
                       splitk, xhat, (long long)Bn * n / 4, zstride / 4, SK);
}

// Round 6
// 634.098 us; speedup vs baseline: 1.2901x; 1.2901x over previous
//
#include <hip/hip_runtime.h>
#include <math.h>

typedef _Float16 hlf4 __attribute__((ext_vector_type(4)));
typedef _Float16 hlf8 __attribute__((ext_vector_type(8)));
typedef float f32x4 __attribute__((ext_vector_type(4)));

// async global->LDS, 16B per lane; lds base must be wave-uniform
static __device__ __forceinline__ void gl_lds16(const void* g, void* l) {
    __builtin_amdgcn_global_load_lds(
        (const __attribute__((address_space(1))) unsigned int*)g,
        (__attribute__((address_space(3))) unsigned int*)l, 16, 0, 0);
}

// ---------------- block reductions (deterministic tree order) ----------------
static __device__ __forceinline__ float blk_sum(float v) {
    __shared__ float sm[256];
    int tid = threadIdx.x;
    sm[tid] = v; __syncthreads();
#pragma unroll
    for (int s = 128; s > 0; s >>= 1) {
        if (tid < s) sm[tid] += sm[tid + s];
        __syncthreads();
    }
    float r = sm[0]; __syncthreads();
    return r;
}

static __device__ __forceinline__ float blk_max(float v) {
    __shared__ float sm[256];
    int tid = threadIdx.x;
    sm[tid] = v; __syncthreads();
#pragma unroll
    for (int s = 128; s > 0; s >>= 1) {
        if (tid < s) sm[tid] = fmaxf(sm[tid], sm[tid + s]);
        __syncthreads();
    }
    float r = sm[0]; __syncthreads();
    return r;
}

// ---------------- C normalizer: per-row norms of gathered rows ----------------
__global__ __launch_bounds__(256) void k_row_norms(
    const float* __restrict__ X, const int* __restrict__ idx,
    float* __restrict__ norms, int n) {
    long long r = idx[blockIdx.x];
    const float* xr = X + r * (long long)n;
    float s = 0.f;
    for (int k = threadIdx.x * 4; k < n; k += 256 * 4) {
        float4 v = *(const float4*)(xr + k);
        s = fmaf(v.x, v.x, s); s = fmaf(v.y, v.y, s);
        s = fmaf(v.z, v.z, s); s = fmaf(v.w, v.w, s);
    }
    float tot = blk_sum(s);
    if (threadIdx.x == 0) norms[blockIdx.x] = sqrtf(tot);
}

__global__ __launch_bounds__(256) void k_cinv(
    const float* __restrict__ norms, int m, int n, float* __restrict__ cinv) {
    float s = 0.f;
    for (int i = threadIdx.x; i < m; i += 256) s += norms[i];
    float tot = blk_sum(s);
    if (threadIdx.x == 0) cinv[0] = (float)m * sqrtf((float)n) / tot;  // 1/C
}

// ---------------- xs = x * (1/C): f32 out + f16 copy ----------------
__global__ __launch_bounds__(256) void k_scale2(
    const float* __restrict__ x, const float* __restrict__ cinv,
    float* __restrict__ y, _Float16* __restrict__ yh, long long total4) {
    float c = cinv[0];
    long long i = blockIdx.x * 256ll + threadIdx.x;
    long long stride = (long long)gridDim.x * 256ll;
    for (; i < total4; i += stride) {
        float4 v = ((const float4*)x)[i];
        v.x *= c; v.y *= c; v.z *= c; v.w *= c;
        ((float4*)y)[i] = v;
        hlf4 o = {(_Float16)v.x, (_Float16)v.y, (_Float16)v.z, (_Float16)v.w};
        ((hlf4*)yh)[i] = o;
    }
}

// ---------------- gather + scale + cvt: Xc_h[r] = f16(X[idx[r]] * cinv) ------
__global__ __launch_bounds__(256) void k_gather_cvt(
    const float* __restrict__ X, const int* __restrict__ idx,
    const float* __restrict__ cinv, _Float16* __restrict__ out, int n) {
    long long r = idx[blockIdx.x];
    float c = cinv[0];
    const float* src = X + r * (long long)n;
    _Float16* dst = out + (long long)blockIdx.x * n;
    for (int k = threadIdx.x * 4; k < n; k += 256 * 4) {
        float4 v = *(const float4*)(src + k);
        hlf4 o = {(_Float16)(v.x * c), (_Float16)(v.y * c),
                  (_Float16)(v.z * c), (_Float16)(v.w * c)};
        *(hlf4*)(dst + k) = o;
    }
}

// ---------------- flat f32 -> f16 ----------------
__global__ __launch_bounds__(256) void k_cvt(
    const float* __restrict__ in, _Float16* __restrict__ out, long long n4) {
    long long i = blockIdx.x * 256ll + threadIdx.x;
    long long stride = (long long)gridDim.x * 256ll;
    for (; i < n4; i += stride) {
        float4 v = ((const float4*)in)[i];
        hlf4 o = {(_Float16)v.x, (_Float16)v.y, (_Float16)v.z, (_Float16)v.w};
        ((hlf4*)out)[i] = o;
    }
}

// ---------------- transpose + cvt: in[R][Cc] f32 -> out[Cc][R] f16 ----------
__global__ __launch_bounds__(256) void k_tcvt(
    const float* __restrict__ in, _Float16* __restrict__ out, int R, int Cc) {
    __shared__ _Float16 t[32][34];
    int tx = threadIdx.x & 31, ty = threadIdx.x >> 5;   // ty 0..7
    int c0 = blockIdx.x * 32, r0 = blockIdx.y * 32;
#pragma unroll
    for (int i = 0; i < 32; i += 8)
        t[ty + i][tx] = (_Float16)in[(long long)(r0 + ty + i) * Cc + c0 + tx];
    __syncthreads();
#pragma unroll
    for (int i = 0; i < 32; i += 8)
        out[(long long)(c0 + ty + i) * R + r0 + tx] = t[tx][ty + i];
}

// ================= m97-structure MFMA NT GEMM (128² tile, 4 waves) ==========
// Known-good R4 kernel; used for the small q/k projections.
__global__ __launch_bounds__(256) void k_gemm4(
    const _Float16* __restrict__ A, int lda,
    const _Float16* __restrict__ B, int ldb,
    float* __restrict__ Cc, long long ldc, int K,
    float* __restrict__ part, long long zstride) {
    __shared__ _Float16 Ah[2][4096];
    __shared__ _Float16 Bh[2][4096];
    const int tid = threadIdx.x;
    const long long m0 = (long long)blockIdx.x * 128;
    const long long n0 = (long long)blockIdx.y * 128;
    const int KC = K / gridDim.z;
    const int kbase = blockIdx.z * KC;
    const int lane = tid & 63, wv = tid >> 6;
    const int wm = (wv >> 1) * 64, wn = (wv & 1) * 64;
    const int fr = lane & 15, fq = lane >> 4;

    const int s0 = tid, s1 = tid + 256;
    const int r0s = s0 >> 2, r1s = s1 >> 2;
    const int g0 = (((s0 & 3) ^ (r0s & 3)) << 3);
    const int g1 = (((s1 & 3) ^ (r1s & 3)) << 3);
    const _Float16* A0 = A + (m0 + r0s) * (long long)lda + kbase + g0;
    const _Float16* A1 = A + (m0 + r1s) * (long long)lda + kbase + g1;
    const _Float16* B0 = B + (n0 + r0s) * (long long)ldb + kbase + g0;
    const _Float16* B1 = B + (n0 + r1s) * (long long)ldb + kbase + g1;

    f32x4 acc[4][4] = {};

    const int NT = KC / 32;
    {
        gl_lds16(A0, &Ah[0][wv * 512]);
        gl_lds16(A1, &Ah[0][2048 + wv * 512]);
        gl_lds16(B0, &Bh[0][wv * 512]);
        gl_lds16(B1, &Bh[0][2048 + wv * 512]);
    }
    __syncthreads();

    for (int kt = 0; kt < NT; ++kt) {
        const int cur = kt & 1;
        if (kt + 1 < NT) {
            const int nx = cur ^ 1;
            const long long ko = (long long)(kt + 1) * 32;
            gl_lds16(A0 + ko, &Ah[nx][wv * 512]);
            gl_lds16(A1 + ko, &Ah[nx][2048 + wv * 512]);
            gl_lds16(B0 + ko, &Bh[nx][wv * 512]);
            gl_lds16(B1 + ko, &Bh[nx][2048 + wv * 512]);
        }
        hlf8 af[4], bf[4];
#pragma unroll
        for (int i = 0; i < 4; ++i) {
            const int r = wm + i * 16 + fr;
            af[i] = *(const hlf8*)&Ah[cur][r * 32 + ((fq ^ (r & 3)) << 3)];
        }
#pragma unroll
        for (int j = 0; j < 4; ++j) {
            const int r = wn + j * 16 + fr;
            bf[j] = *(const hlf8*)&Bh[cur][r * 32 + ((fq ^ (r & 3)) << 3)];
        }
#pragma unroll
        for (int i = 0; i < 4; ++i)
#pragma unroll
            for (int j = 0; j < 4; ++j)
                acc[i][j] = __builtin_amdgcn_mfma_f32_16x16x32_f16(af[i], bf[j], acc[i][j], 0, 0, 0);
        __syncthreads();
    }

    float* outp = (gridDim.z == 1) ? Cc : (part + (long long)blockIdx.z * zstride);
#pragma unroll
    for (int i = 0; i < 4; ++i)
#pragma unroll
        for (int j = 0; j < 4; ++j) {
            float* cp = outp + (m0 + wm + i * 16 + fq * 4) * ldc + (n0 + wn + j * 16 + fr);
#pragma unroll
            for (int r = 0; r < 4; ++r) cp[(long long)r * ldc] = acc[i][j][r];
        }
}

// ========== 256² deep-pipelined NT GEMM (T3+T4+T5, counted vmcnt) ===========
// C[i][j] = sum_k A[i][k]*B[j][k].  BM=BN=256, BK=64, 512 thr / 8 waves
// (2Mx4N, 128x64 each, 8x4 frags of 16x16x32). LDS 128 KiB: 2 dbuf x
// (A[256][64] + B[256][64]) f16. Per K-tile:
//   s_barrier(1)  -> all waves done reading buf^1 (prev tile)
//   issue 8 global_load_lds into buf^1 (next tile)
//   s_waitcnt vmcnt(8)  -> this tile's 8 landed; next tile's 8 stay in flight
//   s_barrier(2)  -> everyone's loads for this tile landed
//   4 MFMA phases {ds_read, lgkmcnt(0)+sched_barrier(0), setprio(1), 16 MFMA}
// Raw s_barrier only (no __syncthreads: that drains vmcnt -> m97 ceiling).
// Swizzle (rule 21): 16B slot p' = p ^ (row&7) applied to BOTH the global
// source of global_load_lds and the frag ds_read -> 2 lanes/bank (free, m136).
__global__ __launch_bounds__(512, 2) void k_g256(
    const _Float16* __restrict__ A, int lda,
    const _Float16* __restrict__ B, int ldb,
    float* __restrict__ Cc, long long ldc, int K,
    float* __restrict__ part, long long zstride) {
    __shared__ _Float16 Ah[2][16384];
    __shared__ _Float16 Bh[2][16384];
    const int tid = threadIdx.x, lane = tid & 63, wv = tid >> 6;

    // XCD-aware bijective remap (all launches keep nwg % 8 == 0)
    const int gx = gridDim.x, gy = gridDim.y;
    int lin = blockIdx.x + gx * (blockIdx.y + gy * blockIdx.z);
    const int cpx = (gx * gy * (int)gridDim.z) >> 3;
    lin = (lin & 7) * cpx + (lin >> 3);
    const int bx = lin % gx; const int rest = lin / gx;
    const int by = rest % gy, bz = rest / gy;

    const long long m0 = (long long)bx * 256;
    const long long n0 = (long long)by * 256;
    const int KC = K / gridDim.z;
    const int kbase = bz * KC;
    const int wm = (wv >> 2) * 128, wn = (wv & 3) * 64;
    const int fr = lane & 15, fq = lane >> 4;

    // staging sources: tile = 2048 16B-slots; thread covers slots j*512+tid.
    // phys slot s = (row<<3)|p holds logical 8-half group g = p ^ (row&7).
    const _Float16* srcA[4];
    const _Float16* srcB[4];
#pragma unroll
    for (int j = 0; j < 4; ++j) {
        const int s = j * 512 + tid;
        const int r = s >> 3, p = s & 7;
        const int g = (p ^ (r & 7)) << 3;
        srcA[j] = A + (m0 + r) * (long long)lda + kbase + g;
        srcB[j] = B + (n0 + r) * (long long)ldb + kbase + g;
    }

    f32x4 acc[8][4] = {};

#define ISSUE8(bufi, kt)                                                      \
    {                                                                         \
        const long long ko_ = (long long)(kt) * 64;                           \
        _Float16* la_ = &Ah[bufi][0];                                         \
        _Float16* lb_ = &Bh[bufi][0];                                         \
        gl_lds16(srcA[0] + ko_, la_ + (0 * 512 + wv * 64) * 8);               \
        gl_lds16(srcB[0] + ko_, lb_ + (0 * 512 + wv * 64) * 8);               \
        gl_lds16(srcA[1] + ko_, la_ + (1 * 512 + wv * 64) * 8);               \
        gl_lds16(srcB[1] + ko_, lb_ + (1 * 512 + wv * 64) * 8);               \
        gl_lds16(srcA[2] + ko_, la_ + (2 * 512 + wv * 64) * 8);               \
        gl_lds16(srcB[2] + ko_, lb_ + (2 * 512 + wv * 64) * 8);               \
        gl_lds16(srcA[3] + ko_, la_ + (3 * 512 + wv * 64) * 8);               \
        gl_lds16(srcB[3] + ko_, lb_ + (3 * 512 + wv * 64) * 8);               \
    }

    const int NT = KC / 64;
    ISSUE8(0, 0);
    asm volatile("s_waitcnt vmcnt(0)" ::: "memory");
    __builtin_amdgcn_s_barrier();

    for (int kt = 0; kt < NT; ++kt) {
        const int cur = kt & 1;
        __builtin_amdgcn_s_barrier();               // (1) buf^1 reads done
        if (kt + 1 < NT) {
            ISSUE8(cur ^ 1, kt + 1);
            asm volatile("s_waitcnt vmcnt(8)" ::: "memory");
        } else {
            asm volatile("s_waitcnt vmcnt(0)" ::: "memory");
        }
        __builtin_amdgcn_s_barrier();               // (2) this tile landed
        __builtin_amdgcn_sched_barrier(0);

        hlf8 af[4][2], bf01[2][2], bf23[2][2];
        // ---- phase 1: A rows 0-63 + B cols 0-31; MFMA quadrant (0-63 x 0-31)
#pragma unroll
        for (int i = 0; i < 4; ++i)
#pragma unroll
            for (int ks = 0; ks < 2; ++ks) {
                const int rr = wm + i * 16 + fr;
                af[i][ks] = *(const hlf8*)&Ah[cur][rr * 64 + ((((ks * 4 + fq)) ^ (rr & 7)) << 3)];
            }
#pragma unroll
        for (int jj = 0; jj < 2; ++jj)
#pragma unroll
            for (int ks = 0; ks < 2; ++ks) {
                const int cc = wn + jj * 16 + fr;
                bf01[jj][ks] = *(const hlf8*)&Bh[cur][cc * 64 + ((((ks * 4 + fq)) ^ (cc & 7)) << 3)];
            }
        asm volatile("s_waitcnt lgkmcnt(0)" ::: "memory");
        __builtin_amdgcn_sched_barrier(0);
        __builtin_amdgcn_s_setprio(1);
#pragma unroll
        for (int i = 0; i < 4; ++i)
#pragma unroll
            for (int jj = 0; jj < 2; ++jj)
#pragma unroll
                for (int ks = 0; ks < 2; ++ks)
                    acc[i][jj] = __builtin_amdgcn_mfma_f32_16x16x32_f16(af[i][ks], bf01[jj][ks], acc[i][jj], 0, 0, 0);
        __builtin_amdgcn_s_setprio(0);

        // ---- phase 2: B cols 32-63; MFMA (0-63 x 32-63)
#pragma unroll
        for (int jj = 0; jj < 2; ++jj)
#pragma unroll
            for (int ks = 0; ks < 2; ++ks) {
                const int cc = wn + (jj + 2) * 16 + fr;
                bf23[jj][ks] = *(const hlf8*)&Bh[cur][cc * 64 + ((((ks * 4 + fq)) ^ (cc & 7)) << 3)];
            }
        asm volatile("s_waitcnt lgkmcnt(0)" ::: "memory");
        __builtin_amdgcn_sched_barrier(0);
        __builtin_amdgcn_s_setprio(1);
#pragma unroll
        for (int i = 0; i < 4; ++i)
#pragma unroll
            for (int jj = 0; jj < 2; ++jj)
#pragma unroll
                for (int ks = 0; ks < 2; ++ks)
                    acc[i][jj + 2] = __builtin_amdgcn_mfma_f32_16x16x32_f16(af[i][ks], bf23[jj][ks], acc[i][jj + 2], 0, 0, 0);
        __builtin_amdgcn_s_setprio(0);

        // ---- phase 3: A rows 64-127; MFMA (64-127 x 0-31)
#pragma unroll
        for (int i = 0; i < 4; ++i)
#pragma unroll
            for (int ks = 0; ks < 2; ++ks) {
                const int rr = wm + (i + 4) * 16 + fr;
                af[i][ks] = *(const hlf8*)&Ah[cur][rr * 64 + ((((ks * 4 + fq)) ^ (rr & 7)) << 3)];
            }
        asm volatile("s_waitcnt lgkmcnt(0)" ::: "memory");
        __builtin_amdgcn_sched_barrier(0);
        __builtin_amdgcn_s_setprio(1);
#pragma unroll
        for (int i = 0; i < 4; ++i)
#pragma unroll
            for (int jj = 0; jj < 2; ++jj)
#pragma unroll
                for (int ks = 0; ks < 2; ++ks)
                    acc[i + 4][jj] = __builtin_amdgcn_mfma_f32_16x16x32_f16(af[i][ks], bf01[jj][ks], acc[i + 4][jj], 0, 0, 0);
        __builtin_amdgcn_s_setprio(0);

        // ---- phase 4: MFMA (64-127 x 32-63), no reads
        __builtin_amdgcn_s_setprio(1);
#pragma unroll
        for (int i = 0; i < 4; ++i)
#pragma unroll
            for (int jj = 0; jj < 2; ++jj)
#pragma unroll
                for (int ks = 0; ks < 2; ++ks)
                    acc[i + 4][jj + 2] = __builtin_amdgcn_mfma_f32_16x16x32_f16(af[i][ks], bf23[jj][ks], acc[i + 4][jj + 2], 0, 0, 0);
        __builtin_amdgcn_s_setprio(0);
    }
#undef ISSUE8

    float* outp = (gridDim.z == 1) ? Cc : (part + (long long)bz * zstride);
    // C/D layout: col=lane&15, row=(lane>>4)*4+reg (m89-verified)
#pragma unroll
    for (int i = 0; i < 8; ++i)
#pragma unroll
        for (int j = 0; j < 4; ++j) {
            float* cp = outp + (m0 + wm + i * 16 + fq * 4) * ldc + (n0 + wn + j * 16 + fr);
#pragma unroll
            for (int r = 0; r < 4; ++r) cp[(long long)r * ldc] = acc[i][j][r];
        }
}

// ---------------- split-K reduction: out = sum_z part[z] ----------------
__global__ __launch_bounds__(256) void k_redux(
    const float* __restrict__ part, float* __restrict__ out,
    long long n4, long long zs4, int Z) {
    long long i = blockIdx.x * 256ll + threadIdx.x;
    long long stride = (long long)gridDim.x * 256ll;
    for (; i < n4; i += stride) {
        float4 s = ((const float4*)part)[i];
        for (int z = 1; z < Z; ++z) {
            float4 t = ((const float4*)part)[i + z * zs4];
            s.x += t.x; s.y += t.y; s.z += t.z; s.w += t.w;
        }
        ((float4*)out)[i] = s;
    }
}

// ---------------- row LayerNorm in-place, width W = CNT*256 ----------------
template <int CNT>
__global__ __launch_bounds__(256) void k_layernorm(
    float* __restrict__ Y, const float* __restrict__ g,
    const float* __restrict__ b, int W) {
    float* yr = Y + (long long)blockIdx.x * W;
    float v[CNT];
    float s = 0.f;
#pragma unroll
    for (int i = 0; i < CNT; ++i) {
        v[i] = yr[threadIdx.x + (i << 8)];
        s += v[i];
    }
    float mu = blk_sum(s) / (float)W;
    float sq = 0.f;
#pragma unroll
    for (int i = 0; i < CNT; ++i) {
        float d = v[i] - mu;
        sq = fmaf(d, d, sq);
    }
    float var = blk_sum(sq) / (float)W;
    float rs = rsqrtf(var + 1e-5f);
#pragma unroll
    for (int i = 0; i < CNT; ++i) {
        int col = threadIdx.x + (i << 8);
        yr[col] = (v[i] - mu) * rs * g[col] + b[col];
    }
}

// -------- row softmax in-place, W = 16384; optional f16 copy of result ------
__global__ __launch_bounds__(256) void k_softmax(
    float* __restrict__ S, _Float16* __restrict__ Sh, float scale) {
    float* sr = S + (long long)blockIdx.x * 16384;
    _Float16* shr = Sh ? Sh + (long long)blockIdx.x * 16384 : nullptr;
    float4 r[16];
    float mx = -1e30f;
#pragma unroll
    for (int i = 0; i < 16; ++i) {
        float4 t = ((const float4*)sr)[threadIdx.x + (i << 8)];
        t.x *= scale; t.y *= scale; t.z *= scale; t.w *= scale;
        r[i] = t;
        mx = fmaxf(mx, fmaxf(fmaxf(t.x, t.y), fmaxf(t.z, t.w)));
    }
    mx = blk_max(mx);
    float sum = 0.f;
#pragma unroll
    for (int i = 0; i < 16; ++i) {
        float4 t = r[i];
        t.x = __expf(t.x - mx); t.y = __expf(t.y - mx);
        t.z = __expf(t.z - mx); t.w = __expf(t.w - mx);
        r[i] = t;
        sum += t.x + t.y + t.z + t.w;
    }
    sum = blk_sum(sum);
    float inv = 1.0f / sum;
#pragma unroll
    for (int i = 0; i < 16; ++i) {
        float4 t = r[i];
        t.x *= inv; t.y *= inv; t.z *= inv; t.w *= inv;
        ((float4*)sr)[threadIdx.x + (i << 8)] = t;
        if (shr) {
            hlf4 o = {(_Float16)t.x, (_Float16)t.y, (_Float16)t.z, (_Float16)t.w};
            ((hlf4*)shr)[threadIdx.x + (i << 8)] = o;
        }
    }
}

extern "C" void kernel_launch(void* const* d_in, const int* in_sizes, int n_in,
                              void* d_out, int out_size, void* d_ws, size_t ws_size,
                              hipStream_t stream) {
    const float* x      = (const float*)d_in[0];
    const float* X_data = (const float*)d_in[1];
    const int*   midx   = (const int*)d_in[2];
    const float* W_q    = (const float*)d_in[3];
    const float* W_k    = (const float*)d_in[4];
    const float* W_v    = (const float*)d_in[5];
    const float* g_q    = (const float*)d_in[6];
    const float* b_q    = (const float*)d_in[7];
    const float* g_k    = (const float*)d_in[8];
    const float* b_k    = (const float*)d_in[9];
    const float* g_v    = (const float*)d_in[10];
    const float* b_v    = (const float*)d_in[11];

    const int n  = in_sizes[10];        // 1024
    const int a  = in_sizes[6];         // 256
    const int m  = in_sizes[2];         // 16384
    const int Bn = in_sizes[0] / n;     // 4096

    // output layout: xs | x_hat | attn | v
    float* out  = (float*)d_out;
    float* xs   = out;
    float* xhat = xs + (long long)Bn * n;
    float* attn = xhat + (long long)Bn * n;
    float* vout = attn + (long long)Bn * m;

    // workspace carving (256B aligned). [qmat .. k_h] (~73 MB) is dead before
    // the x_hat GEMM, so the 64 MB split-K partial buffer aliases it.
    char* wp = (char*)d_ws;
    auto carve = [&](size_t bytes) -> char* {
        char* r = wp; wp += (bytes + 255) & ~(size_t)255; return r;
    };
    float*     norms = (float*)carve((size_t)m * 4);
    float*     cinv  = (float*)carve(16);
    char*      alias0 = wp;
    float*     qmat  = (float*)carve((size_t)Bn * a * 4);
    float*     kmat  = (float*)carve((size_t)m * a * 4);
    _Float16*  xs_h  = (_Float16*)carve((size_t)Bn * n * 2);
    _Float16*  Xc_h  = (_Float16*)carve((size_t)m * n * 2);
    _Float16*  Wq_h  = (_Float16*)carve((size_t)a * n * 2);
    _Float16*  Wk_h  = (_Float16*)carve((size_t)a * n * 2);
    _Float16*  Wv_h  = (_Float16*)carve((size_t)n * n * 2);
    _Float16*  q_h   = (_Float16*)carve((size_t)Bn * a * 2);
    _Float16*  k_h   = (_Float16*)carve((size_t)m * a * 2);
    float*     splitk = (float*)alias0;
    const int  SK = 4;                                    // SK*Bn*n*4 = 64MB <= 73MB
    _Float16*  vT_h  = (_Float16*)carve((size_t)n * m * 2);
    size_t used = (size_t)(wp - (char*)d_ws);
    _Float16* attn_h = nullptr;
    if (ws_size >= used + (size_t)Bn * m * 2 + 256)
        attn_h = (_Float16*)carve((size_t)Bn * m * 2);

    // 1) C normalizer
    hipLaunchKernelGGL(k_row_norms, dim3(m), dim3(256), 0, stream, X_data, midx, norms, n);
    hipLaunchKernelGGL(k_cinv, dim3(1), dim3(256), 0, stream, norms, m, n, cinv);

    // 2) xs = x/C (f32 + f16); gathered+scaled Xc in f16
    hipLaunchKernelGGL(k_scale2, dim3(2048), dim3(256), 0, stream,
                       x, cinv, xs, xs_h, (long long)Bn * n / 4);
    hipLaunchKernelGGL(k_gather_cvt, dim3(m), dim3(256), 0, stream,
                       X_data, midx, cinv, Xc_h, n);

    // 3) weights -> f16
    hipLaunchKernelGGL(k_cvt, dim3(256), dim3(256), 0, stream, W_q, Wq_h, (long long)a * n / 4);
    hipLaunchKernelGGL(k_cvt, dim3(256), dim3(256), 0, stream, W_k, Wk_h, (long long)a * n / 4);
    hipLaunchKernelGGL(k_cvt, dim3(1024), dim3(256), 0, stream, W_v, Wv_h, (long long)n * n / 4);

    // 4) projections: q,k on 128² m97 kernel; v on the 256² pipelined kernel
    hipLaunchKernelGGL(k_gemm4, dim3(Bn / 128, a / 128), dim3(256), 0, stream,
                       xs_h, n, Wq_h, n, qmat, a, n, (float*)nullptr, 0ll);
    hipLaunchKernelGGL(k_gemm4, dim3(m / 128, a / 128), dim3(256), 0, stream,
                       Xc_h, n, Wk_h, n, kmat, a, n, (float*)nullptr, 0ll);
    hipLaunchKernelGGL(k_g256, dim3(m / 256, n / 256), dim3(512), 0, stream,
                       Xc_h, n, Wv_h, n, vout, n, n, (float*)nullptr, 0ll);

    // 5) LayerNorms (f32) + f16 copies of q,k and transposed v
    hipLaunchKernelGGL(k_layernorm<1>, dim3(Bn), dim3(256), 0, stream, qmat, g_q, b_q, a);
    hipLaunchKernelGGL(k_layernorm<1>, dim3(m),  dim3(256), 0, stream, kmat, g_k, b_k, a);
    hipLaunchKernelGGL(k_layernorm<4>, dim3(m),  dim3(256), 0, stream, vout, g_v, b_v, n);
    hipLaunchKernelGGL(k_cvt, dim3(1024), dim3(256), 0, stream, qmat, q_h, (long long)Bn * a / 4);
    hipLaunchKernelGGL(k_cvt, dim3(4096), dim3(256), 0, stream, kmat, k_h, (long long)m * a / 4);
    hipLaunchKernelGGL(k_tcvt, dim3(n / 32, m / 32), dim3(256), 0, stream, vout, vT_h, m, n);

    // 6) S = q k^T (f32 logits) on 256² kernel, softmax in place (+f16 copy)
    hipLaunchKernelGGL(k_g256, dim3(Bn / 256, m / 256), dim3(512), 0, stream,
                       q_h, a, k_h, a, attn, m, a, (float*)nullptr, 0ll);
    float sc = 1.0f / sqrtf((float)a);
    hipLaunchKernelGGL(k_softmax, dim3(Bn), dim3(256), 0, stream, attn, attn_h, sc);

    // 7) x_hat = attn @ v, 256² kernel with split-K=4, then reduce
    long long zstride = (long long)Bn * n;
    if (attn_h) {
        hipLaunchKernelGGL(k_g256, dim3(Bn / 256, n / 256, SK), dim3(512), 0, stream,
                           attn_h, m, vT_h, m, xhat, n, m, splitk, zstride);
    } else {
        hipLaunchKernelGGL(k_g256, dim3(Bn / 256, n / 256, SK), dim3(512), 0, stream,
                           (const _Float16*)attn, m, vT_h, m, xhat, n, m, splitk, zstride);
    }
    hipLaunchKernelGGL(k_redux, dim3(2048), dim3(256), 0, stream,
                       splitk, xhat, (long long)Bn * n / 4, zstride / 4, SK);
}

// Round 7
// 614.362 us; speedup vs baseline: 1.3316x; 1.0321x over previous
//
#include <hip/hip_runtime.h>
#include <math.h>

typedef _Float16 hlf4 __attribute__((ext_vector_type(4)));
typedef _Float16 hlf8 __attribute__((ext_vector_type(8)));
typedef float f32x4 __attribute__((ext_vector_type(4)));

// async global->LDS, 16B per lane; lds base must be wave-uniform
static __device__ __forceinline__ void gl_lds16(const void* g, void* l) {
    __builtin_amdgcn_global_load_lds(
        (const __attribute__((address_space(1))) unsigned int*)g,
        (__attribute__((address_space(3))) unsigned int*)l, 16, 0, 0);
}

// ---------------- block reductions (deterministic tree order) ----------------
static __device__ __forceinline__ float blk_sum(float v) {
    __shared__ float sm[256];
    int tid = threadIdx.x;
    sm[tid] = v; __syncthreads();
#pragma unroll
    for (int s = 128; s > 0; s >>= 1) {
        if (tid < s) sm[tid] += sm[tid + s];
        __syncthreads();
    }
    float r = sm[0]; __syncthreads();
    return r;
}

static __device__ __forceinline__ float blk_max(float v) {
    __shared__ float sm[256];
    int tid = threadIdx.x;
    sm[tid] = v; __syncthreads();
#pragma unroll
    for (int s = 128; s > 0; s >>= 1) {
        if (tid < s) sm[tid] = fmaxf(sm[tid], sm[tid + s]);
        __syncthreads();
    }
    float r = sm[0]; __syncthreads();
    return r;
}

// ---------------- C normalizer: per-row norms of gathered rows ----------------
__global__ __launch_bounds__(256) void k_row_norms(
    const float* __restrict__ X, const int* __restrict__ idx,
    float* __restrict__ norms, int n) {
    long long r = idx[blockIdx.x];
    const float* xr = X + r * (long long)n;
    float s = 0.f;
    for (int k = threadIdx.x * 4; k < n; k += 256 * 4) {
        float4 v = *(const float4*)(xr + k);
        s = fmaf(v.x, v.x, s); s = fmaf(v.y, v.y, s);
        s = fmaf(v.z, v.z, s); s = fmaf(v.w, v.w, s);
    }
    float tot = blk_sum(s);
    if (threadIdx.x == 0) norms[blockIdx.x] = sqrtf(tot);
}

__global__ __launch_bounds__(256) void k_cinv(
    const float* __restrict__ norms, int m, int n, float* __restrict__ cinv) {
    float s = 0.f;
    for (int i = threadIdx.x; i < m; i += 256) s += norms[i];
    float tot = blk_sum(s);
    if (threadIdx.x == 0) cinv[0] = (float)m * sqrtf((float)n) / tot;  // 1/C
}

// ---------------- xs = x * (1/C): f32 out + f16 copy ----------------
__global__ __launch_bounds__(256) void k_scale2(
    const float* __restrict__ x, const float* __restrict__ cinv,
    float* __restrict__ y, _Float16* __restrict__ yh, long long total4) {
    float c = cinv[0];
    long long i = blockIdx.x * 256ll + threadIdx.x;
    long long stride = (long long)gridDim.x * 256ll;
    for (; i < total4; i += stride) {
        float4 v = ((const float4*)x)[i];
        v.x *= c; v.y *= c; v.z *= c; v.w *= c;
        ((float4*)y)[i] = v;
        hlf4 o = {(_Float16)v.x, (_Float16)v.y, (_Float16)v.z, (_Float16)v.w};
        ((hlf4*)yh)[i] = o;
    }
}

// ---------------- gather + scale + cvt: Xc_h[r] = f16(X[idx[r]] * cinv) ------
__global__ __launch_bounds__(256) void k_gather_cvt(
    const float* __restrict__ X, const int* __restrict__ idx,
    const float* __restrict__ cinv, _Float16* __restrict__ out, int n) {
    long long r = idx[blockIdx.x];
    float c = cinv[0];
    const float* src = X + r * (long long)n;
    _Float16* dst = out + (long long)blockIdx.x * n;
    for (int k = threadIdx.x * 4; k < n; k += 256 * 4) {
        float4 v = *(const float4*)(src + k);
        hlf4 o = {(_Float16)(v.x * c), (_Float16)(v.y * c),
                  (_Float16)(v.z * c), (_Float16)(v.w * c)};
        *(hlf4*)(dst + k) = o;
    }
}

// ---------------- flat f32 -> f16 with scalar scale ----------------
__global__ __launch_bounds__(256) void k_cvt(
    const float* __restrict__ in, _Float16* __restrict__ out, long long n4,
    float sc) {
    long long i = blockIdx.x * 256ll + threadIdx.x;
    long long stride = (long long)gridDim.x * 256ll;
    for (; i < n4; i += stride) {
        float4 v = ((const float4*)in)[i];
        hlf4 o = {(_Float16)(v.x * sc), (_Float16)(v.y * sc),
                  (_Float16)(v.z * sc), (_Float16)(v.w * sc)};
        ((hlf4*)out)[i] = o;
    }
}

// ---------------- transpose + cvt: in[R][Cc] f32 -> out[Cc][R] f16 ----------
__global__ __launch_bounds__(256) void k_tcvt(
    const float* __restrict__ in, _Float16* __restrict__ out, int R, int Cc) {
    __shared__ _Float16 t[32][34];
    int tx = threadIdx.x & 31, ty = threadIdx.x >> 5;   // ty 0..7
    int c0 = blockIdx.x * 32, r0 = blockIdx.y * 32;
#pragma unroll
    for (int i = 0; i < 32; i += 8)
        t[ty + i][tx] = (_Float16)in[(long long)(r0 + ty + i) * Cc + c0 + tx];
    __syncthreads();
#pragma unroll
    for (int i = 0; i < 32; i += 8)
        out[(long long)(c0 + ty + i) * R + r0 + tx] = t[tx][ty + i];
}

// ================= m97-structure MFMA NT GEMM (128² tile, 4 waves) ==========
// Known-good R4 kernel; used for the small q/k projections.
__global__ __launch_bounds__(256) void k_gemm4(
    const _Float16* __restrict__ A, int lda,
    const _Float16* __restrict__ B, int ldb,
    float* __restrict__ Cc, long long ldc, int K,
    float* __restrict__ part, long long zstride) {
    __shared__ _Float16 Ah[2][4096];
    __shared__ _Float16 Bh[2][4096];
    const int tid = threadIdx.x;
    const long long m0 = (long long)blockIdx.x * 128;
    const long long n0 = (long long)blockIdx.y * 128;
    const int KC = K / gridDim.z;
    const int kbase = blockIdx.z * KC;
    const int lane = tid & 63, wv = tid >> 6;
    const int wm = (wv >> 1) * 64, wn = (wv & 1) * 64;
    const int fr = lane & 15, fq = lane >> 4;

    const int s0 = tid, s1 = tid + 256;
    const int r0s = s0 >> 2, r1s = s1 >> 2;
    const int g0 = (((s0 & 3) ^ (r0s & 3)) << 3);
    const int g1 = (((s1 & 3) ^ (r1s & 3)) << 3);
    const _Float16* A0 = A + (m0 + r0s) * (long long)lda + kbase + g0;
    const _Float16* A1 = A + (m0 + r1s) * (long long)lda + kbase + g1;
    const _Float16* B0 = B + (n0 + r0s) * (long long)ldb + kbase + g0;
    const _Float16* B1 = B + (n0 + r1s) * (long long)ldb + kbase + g1;

    f32x4 acc[4][4] = {};

    const int NT = KC / 32;
    {
        gl_lds16(A0, &Ah[0][wv * 512]);
        gl_lds16(A1, &Ah[0][2048 + wv * 512]);
        gl_lds16(B0, &Bh[0][wv * 512]);
        gl_lds16(B1, &Bh[0][2048 + wv * 512]);
    }
    __syncthreads();

    for (int kt = 0; kt < NT; ++kt) {
        const int cur = kt & 1;
        if (kt + 1 < NT) {
            const int nx = cur ^ 1;
            const long long ko = (long long)(kt + 1) * 32;
            gl_lds16(A0 + ko, &Ah[nx][wv * 512]);
            gl_lds16(A1 + ko, &Ah[nx][2048 + wv * 512]);
            gl_lds16(B0 + ko, &Bh[nx][wv * 512]);
            gl_lds16(B1 + ko, &Bh[nx][2048 + wv * 512]);
        }
        hlf8 af[4], bf[4];
#pragma unroll
        for (int i = 0; i < 4; ++i) {
            const int r = wm + i * 16 + fr;
            af[i] = *(const hlf8*)&Ah[cur][r * 32 + ((fq ^ (r & 3)) << 3)];
        }
#pragma unroll
        for (int j = 0; j < 4; ++j) {
            const int r = wn + j * 16 + fr;
            bf[j] = *(const hlf8*)&Bh[cur][r * 32 + ((fq ^ (r & 3)) << 3)];
        }
#pragma unroll
        for (int i = 0; i < 4; ++i)
#pragma unroll
            for (int j = 0; j < 4; ++j)
                acc[i][j] = __builtin_amdgcn_mfma_f32_16x16x32_f16(af[i], bf[j], acc[i][j], 0, 0, 0);
        __syncthreads();
    }

    float* outp = (gridDim.z == 1) ? Cc : (part + (long long)blockIdx.z * zstride);
#pragma unroll
    for (int i = 0; i < 4; ++i)
#pragma unroll
        for (int j = 0; j < 4; ++j) {
            float* cp = outp + (m0 + wm + i * 16 + fq * 4) * ldc + (n0 + wn + j * 16 + fr);
#pragma unroll
            for (int r = 0; r < 4; ++r) cp[(long long)r * ldc] = acc[i][j][r];
        }
}

// ========== 256² deep-pipelined NT GEMM, m201 phase rhythm ==================
// C = A·B^T.  BM=BN=256, BK=64, 512 thr / 8 waves (2Mx4N, 128x64 each).
// LDS 128 KiB dbuf. 2-TILE-AHEAD staging: all 8 global_load_lds for tile
// kt+2 issued at tile kt's P4 (into the buffer whose reads finished at P3);
// tile entry waits vmcnt(8) -> one tile's loads always in flight, NEVER
// drained mid-loop (T4). Phases (T3): reads BEFORE barrier, lgkmcnt(0)
// after, sched_barrier (rule 18), setprio around MFMA (T5):
//   P1: rd A-rh0(8)+B-ch0(4) | bar | lgkm0 | 16 MFMA q00 | bar
//   P2: rd B-ch1(4)          | bar | lgkm0 | 16 MFMA q01 | bar
//   P3: rd A-rh1(8)          | bar | lgkm0 | 16 MFMA q10 | bar
//   P4: ISSUE8(kt+2)               |         16 MFMA q11 (regs only)
// Swizzle (rule 21, 0-conflict verified R6): phys 16B-slot p holds k-group
// p^(row&7); applied to global source AND frag reads.
// OUT16=1: epilogue converts acc to f16 into (hlf*)Cc (pre-scaled logits).
template <int OUT16>
__global__ __launch_bounds__(512, 2) void k_g256(
    const _Float16* __restrict__ A, int lda,
    const _Float16* __restrict__ B, int ldb,
    void* __restrict__ Cc, long long ldc, int K,
    float* __restrict__ part, long long zstride) {
    __shared__ _Float16 Ah[2][16384];
    __shared__ _Float16 Bh[2][16384];
    const int tid = threadIdx.x, lane = tid & 63, wv = tid >> 6;

    // XCD-aware bijective remap (all launches keep nwg % 8 == 0)
    const int gx = gridDim.x, gy = gridDim.y;
    int lin = blockIdx.x + gx * (blockIdx.y + gy * blockIdx.z);
    const int cpx = (gx * gy * (int)gridDim.z) >> 3;
    lin = (lin & 7) * cpx + (lin >> 3);
    const int bx = lin % gx; const int rest = lin / gx;
    const int by = rest % gy, bz = rest / gy;

    const long long m0 = (long long)bx * 256;
    const long long n0 = (long long)by * 256;
    const int KC = K / gridDim.z;
    const int kbase = bz * KC;
    const int wm = (wv >> 2) * 128, wn = (wv & 3) * 64;
    const int fr = lane & 15, fq = lane >> 4;

    // staging sources: tile = 2048 16B-slots; thread covers slots j*512+tid.
    const _Float16* srcA[4];
    const _Float16* srcB[4];
#pragma unroll
    for (int j = 0; j < 4; ++j) {
        const int s = j * 512 + tid;
        const int r = s >> 3, p = s & 7;
        const int g = (p ^ (r & 7)) << 3;
        srcA[j] = A + (m0 + r) * (long long)lda + kbase + g;
        srcB[j] = B + (n0 + r) * (long long)ldb + kbase + g;
    }

    f32x4 acc[8][4] = {};

#define ISSUE8(bufi, kt)                                                      \
    {                                                                         \
        const long long ko_ = (long long)(kt) * 64;                           \
        _Float16* la_ = &Ah[bufi][0];                                         \
        _Float16* lb_ = &Bh[bufi][0];                                         \
        gl_lds16(srcA[0] + ko_, la_ + (0 * 512 + wv * 64) * 8);               \
        gl_lds16(srcB[0] + ko_, lb_ + (0 * 512 + wv * 64) * 8);               \
        gl_lds16(srcA[1] + ko_, la_ + (1 * 512 + wv * 64) * 8);               \
        gl_lds16(srcB[1] + ko_, lb_ + (1 * 512 + wv * 64) * 8);               \
        gl_lds16(srcA[2] + ko_, la_ + (2 * 512 + wv * 64) * 8);               \
        gl_lds16(srcB[2] + ko_, lb_ + (2 * 512 + wv * 64) * 8);               \
        gl_lds16(srcA[3] + ko_, la_ + (3 * 512 + wv * 64) * 8);               \
        gl_lds16(srcB[3] + ko_, lb_ + (3 * 512 + wv * 64) * 8);               \
    }

    const int NT = KC / 64;       // requires NT >= 2 (K >= 128 always here)
    ISSUE8(0, 0);
    ISSUE8(1, 1);

    for (int kt = 0; kt < NT; ++kt) {
        const int cur = kt & 1;
        // entry: this tile's loads landed; next tile's stay in flight
        if (kt + 1 < NT) asm volatile("s_waitcnt vmcnt(8)" ::: "memory");
        else             asm volatile("s_waitcnt vmcnt(0)" ::: "memory");
        __builtin_amdgcn_s_barrier();

        hlf8 a0[4][2], a1[4][2], b0[2][2], b1[2][2];
        // ---------------- P1: read A-rh0 + B-ch0, MFMA q00 ----------------
#pragma unroll
        for (int i = 0; i < 4; ++i)
#pragma unroll
            for (int ks = 0; ks < 2; ++ks) {
                const int rr = wm + i * 16 + fr;
                a0[i][ks] = *(const hlf8*)&Ah[cur][rr * 64 + (((ks * 4 + fq) ^ (rr & 7)) << 3)];
            }
#pragma unroll
        for (int jj = 0; jj < 2; ++jj)
#pragma unroll
            for (int ks = 0; ks < 2; ++ks) {
                const int cc = wn + jj * 16 + fr;
                b0[jj][ks] = *(const hlf8*)&Bh[cur][cc * 64 + (((ks * 4 + fq) ^ (cc & 7)) << 3)];
            }
        __builtin_amdgcn_s_barrier();
        asm volatile("s_waitcnt lgkmcnt(0)" ::: "memory");
        __builtin_amdgcn_sched_barrier(0);
        __builtin_amdgcn_s_setprio(1);
#pragma unroll
        for (int i = 0; i < 4; ++i)
#pragma unroll
            for (int jj = 0; jj < 2; ++jj)
#pragma unroll
                for (int ks = 0; ks < 2; ++ks)
                    acc[i][jj] = __builtin_amdgcn_mfma_f32_16x16x32_f16(a0[i][ks], b0[jj][ks], acc[i][jj], 0, 0, 0);
        __builtin_amdgcn_s_setprio(0);
        __builtin_amdgcn_s_barrier();

        // ---------------- P2: read B-ch1, MFMA q01 ----------------
#pragma unroll
        for (int jj = 0; jj < 2; ++jj)
#pragma unroll
            for (int ks = 0; ks < 2; ++ks) {
                const int cc = wn + (jj + 2) * 16 + fr;
                b1[jj][ks] = *(const hlf8*)&Bh[cur][cc * 64 + (((ks * 4 + fq) ^ (cc & 7)) << 3)];
            }
        __builtin_amdgcn_s_barrier();
        asm volatile("s_waitcnt lgkmcnt(0)" ::: "memory");
        __builtin_amdgcn_sched_barrier(0);
        __builtin_amdgcn_s_setprio(1);
#pragma unroll
        for (int i = 0; i < 4; ++i)
#pragma unroll
            for (int jj = 0; jj < 2; ++jj)
#pragma unroll
                for (int ks = 0; ks < 2; ++ks)
                    acc[i][jj + 2] = __builtin_amdgcn_mfma_f32_16x16x32_f16(a0[i][ks], b1[jj][ks], acc[i][jj + 2], 0, 0, 0);
        __builtin_amdgcn_s_setprio(0);
        __builtin_amdgcn_s_barrier();

        // ---------------- P3: read A-rh1, MFMA q10 ----------------
#pragma unroll
        for (int i = 0; i < 4; ++i)
#pragma unroll
            for (int ks = 0; ks < 2; ++ks) {
                const int rr = wm + (i + 4) * 16 + fr;
                a1[i][ks] = *(const hlf8*)&Ah[cur][rr * 64 + (((ks * 4 + fq) ^ (rr & 7)) << 3)];
            }
        __builtin_amdgcn_s_barrier();
        asm volatile("s_waitcnt lgkmcnt(0)" ::: "memory");
        __builtin_amdgcn_sched_barrier(0);
        __builtin_amdgcn_s_setprio(1);
#pragma unroll
        for (int i = 0; i < 4; ++i)
#pragma unroll
            for (int jj = 0; jj < 2; ++jj)
#pragma unroll
                for (int ks = 0; ks < 2; ++ks)
                    acc[i + 4][jj] = __builtin_amdgcn_mfma_f32_16x16x32_f16(a1[i][ks], b0[jj][ks], acc[i + 4][jj], 0, 0, 0);
        __builtin_amdgcn_s_setprio(0);
        __builtin_amdgcn_s_barrier();

        // ---- P4: issue stage for kt+2 into just-freed buf, MFMA q11 ----
        if (kt + 2 < NT) ISSUE8(cur, kt + 2);
        __builtin_amdgcn_s_setprio(1);
#pragma unroll
        for (int i = 0; i < 4; ++i)
#pragma unroll
            for (int jj = 0; jj < 2; ++jj)
#pragma unroll
                for (int ks = 0; ks < 2; ++ks)
                    acc[i + 4][jj + 2] = __builtin_amdgcn_mfma_f32_16x16x32_f16(a1[i][ks], b1[jj][ks], acc[i + 4][jj + 2], 0, 0, 0);
        __builtin_amdgcn_s_setprio(0);
        // next iteration's entry vmcnt+barrier closes the tile
    }
#undef ISSUE8

    // C/D layout: col=lane&15, row=(lane>>4)*4+reg (m89-verified)
    if constexpr (OUT16) {
        _Float16* op = (_Float16*)Cc;
#pragma unroll
        for (int i = 0; i < 8; ++i)
#pragma unroll
            for (int j = 0; j < 4; ++j) {
                _Float16* cp = op + (m0 + wm + i * 16 + fq * 4) * ldc + (n0 + wn + j * 16 + fr);
#pragma unroll
                for (int r = 0; r < 4; ++r) cp[(long long)r * ldc] = (_Float16)acc[i][j][r];
            }
    } else {
        float* outp = (gridDim.z == 1) ? (float*)Cc : (part + (long long)bz * zstride);
#pragma unroll
        for (int i = 0; i < 8; ++i)
#pragma unroll
            for (int j = 0; j < 4; ++j) {
                float* cp = outp + (m0 + wm + i * 16 + fq * 4) * ldc + (n0 + wn + j * 16 + fr);
#pragma unroll
                for (int r = 0; r < 4; ++r) cp[(long long)r * ldc] = acc[i][j][r];
            }
    }
}

// ---------------- split-K reduction: out = sum_z part[z] ----------------
__global__ __launch_bounds__(256) void k_redux(
    const float* __restrict__ part, float* __restrict__ out,
    long long n4, long long zs4, int Z) {
    long long i = blockIdx.x * 256ll + threadIdx.x;
    long long stride = (long long)gridDim.x * 256ll;
    for (; i < n4; i += stride) {
        float4 s = ((const float4*)part)[i];
        for (int z = 1; z < Z; ++z) {
            float4 t = ((const float4*)part)[i + z * zs4];
            s.x += t.x; s.y += t.y; s.z += t.z; s.w += t.w;
        }
        ((float4*)out)[i] = s;
    }
}

// ---------------- row LayerNorm in-place, width W = CNT*256 ----------------
template <int CNT>
__global__ __launch_bounds__(256) void k_layernorm(
    float* __restrict__ Y, const float* __restrict__ g,
    const float* __restrict__ b, int W) {
    float* yr = Y + (long long)blockIdx.x * W;
    float v[CNT];
    float s = 0.f;
#pragma unroll
    for (int i = 0; i < CNT; ++i) {
        v[i] = yr[threadIdx.x + (i << 8)];
        s += v[i];
    }
    float mu = blk_sum(s) / (float)W;
    float sq = 0.f;
#pragma unroll
    for (int i = 0; i < CNT; ++i) {
        float d = v[i] - mu;
        sq = fmaf(d, d, sq);
    }
    float var = blk_sum(sq) / (float)W;
    float rs = rsqrtf(var + 1e-5f);
#pragma unroll
    for (int i = 0; i < CNT; ++i) {
        int col = threadIdx.x + (i << 8);
        yr[col] = (v[i] - mu) * rs * g[col] + b[col];
    }
}

// -------- softmax over f16 pre-scaled logits, W = 16384 ---------------------
// reads Sh (f16), writes attn f32 (output) + renormalized f16 back to Sh.
__global__ __launch_bounds__(256) void k_softmax_h(
    _Float16* __restrict__ Sh, float* __restrict__ attnf) {
    _Float16* sr = Sh + (long long)blockIdx.x * 16384;
    float* ar = attnf + (long long)blockIdx.x * 16384;
    float4 r[16];
    float mx = -1e30f;
#pragma unroll
    for (int i = 0; i < 16; ++i) {
        hlf4 h = ((const hlf4*)sr)[threadIdx.x + (i << 8)];
        float4 t = {(float)h[0], (float)h[1], (float)h[2], (float)h[3]};
        r[i] = t;
        mx = fmaxf(mx, fmaxf(fmaxf(t.x, t.y), fmaxf(t.z, t.w)));
    }
    mx = blk_max(mx);
    float sum = 0.f;
#pragma unroll
    for (int i = 0; i < 16; ++i) {
        float4 t = r[i];
        t.x = __expf(t.x - mx); t.y = __expf(t.y - mx);
        t.z = __expf(t.z - mx); t.w = __expf(t.w - mx);
        r[i] = t;
        sum += t.x + t.y + t.z + t.w;
    }
    sum = blk_sum(sum);
    float inv = 1.0f / sum;
#pragma unroll
    for (int i = 0; i < 16; ++i) {
        float4 t = r[i];
        t.x *= inv; t.y *= inv; t.z *= inv; t.w *= inv;
        ((float4*)ar)[threadIdx.x + (i << 8)] = t;
        hlf4 o = {(_Float16)t.x, (_Float16)t.y, (_Float16)t.z, (_Float16)t.w};
        ((hlf4*)sr)[threadIdx.x + (i << 8)] = o;
    }
}

// -------- legacy f32-logits softmax (fallback path only) --------------------
__global__ __launch_bounds__(256) void k_softmax(
    float* __restrict__ S, _Float16* __restrict__ Sh, float scale) {
    float* sr = S + (long long)blockIdx.x * 16384;
    _Float16* shr = Sh ? Sh + (long long)blockIdx.x * 16384 : nullptr;
    float4 r[16];
    float mx = -1e30f;
#pragma unroll
    for (int i = 0; i < 16; ++i) {
        float4 t = ((const float4*)sr)[threadIdx.x + (i << 8)];
        t.x *= scale; t.y *= scale; t.z *= scale; t.w *= scale;
        r[i] = t;
        mx = fmaxf(mx, fmaxf(fmaxf(t.x, t.y), fmaxf(t.z, t.w)));
    }
    mx = blk_max(mx);
    float sum = 0.f;
#pragma unroll
    for (int i = 0; i < 16; ++i) {
        float4 t = r[i];
        t.x = __expf(t.x - mx); t.y = __expf(t.y - mx);
        t.z = __expf(t.z - mx); t.w = __expf(t.w - mx);
        r[i] = t;
        sum += t.x + t.y + t.z + t.w;
    }
    sum = blk_sum(sum);
    float inv = 1.0f / sum;
#pragma unroll
    for (int i = 0; i < 16; ++i) {
        float4 t = r[i];
        t.x *= inv; t.y *= inv; t.z *= inv; t.w *= inv;
        ((float4*)sr)[threadIdx.x + (i << 8)] = t;
        if (shr) {
            hlf4 o = {(_Float16)t.x, (_Float16)t.y, (_Float16)t.z, (_Float16)t.w};
            ((hlf4*)shr)[threadIdx.x + (i << 8)] = o;
        }
    }
}

extern "C" void kernel_launch(void* const* d_in, const int* in_sizes, int n_in,
                              void* d_out, int out_size, void* d_ws, size_t ws_size,
                              hipStream_t stream) {
    const float* x      = (const float*)d_in[0];
    const float* X_data = (const float*)d_in[1];
    const int*   midx   = (const int*)d_in[2];
    const float* W_q    = (const float*)d_in[3];
    const float* W_k    = (const float*)d_in[4];
    const float* W_v    = (const float*)d_in[5];
    const float* g_q    = (const float*)d_in[6];
    const float* b_q    = (const float*)d_in[7];
    const float* g_k    = (const float*)d_in[8];
    const float* b_k    = (const float*)d_in[9];
    const float* g_v    = (const float*)d_in[10];
    const float* b_v    = (const float*)d_in[11];

    const int n  = in_sizes[10];        // 1024
    const int a  = in_sizes[6];         // 256
    const int m  = in_sizes[2];         // 16384
    const int Bn = in_sizes[0] / n;     // 4096

    // output layout: xs | x_hat | attn | v
    float* out  = (float*)d_out;
    float* xs   = out;
    float* xhat = xs + (long long)Bn * n;
    float* attn = xhat + (long long)Bn * n;
    float* vout = attn + (long long)Bn * m;

    // workspace carving (256B aligned). [qmat .. k_h] (~73 MB) is dead before
    // the x_hat GEMM, so the 64 MB split-K partial buffer aliases it.
    char* wp = (char*)d_ws;
    auto carve = [&](size_t bytes) -> char* {
        char* r = wp; wp += (bytes + 255) & ~(size_t)255; return r;
    };
    float*     norms = (float*)carve((size_t)m * 4);
    float*     cinv  = (float*)carve(16);
    char*      alias0 = wp;
    float*     qmat  = (float*)carve((size_t)Bn * a * 4);
    float*     kmat  = (float*)carve((size_t)m * a * 4);
    _Float16*  xs_h  = (_Float16*)carve((size_t)Bn * n * 2);
    _Float16*  Xc_h  = (_Float16*)carve((size_t)m * n * 2);
    _Float16*  Wq_h  = (_Float16*)carve((size_t)a * n * 2);
    _Float16*  Wk_h  = (_Float16*)carve((size_t)a * n * 2);
    _Float16*  Wv_h  = (_Float16*)carve((size_t)n * n * 2);
    _Float16*  q_h   = (_Float16*)carve((size_t)Bn * a * 2);
    _Float16*  k_h   = (_Float16*)carve((size_t)m * a * 2);
    float*     splitk = (float*)alias0;
    const int  SK = 4;                                    // SK*Bn*n*4 = 64MB <= 73MB
    _Float16*  vT_h  = (_Float16*)carve((size_t)n * m * 2);
    size_t used = (size_t)(wp - (char*)d_ws);
    _Float16* attn_h = nullptr;
    if (ws_size >= used + (size_t)Bn * m * 2 + 256)
        attn_h = (_Float16*)carve((size_t)Bn * m * 2);

    // 1) C normalizer
    hipLaunchKernelGGL(k_row_norms, dim3(m), dim3(256), 0, stream, X_data, midx, norms, n);
    hipLaunchKernelGGL(k_cinv, dim3(1), dim3(256), 0, stream, norms, m, n, cinv);

    // 2) xs = x/C (f32 + f16); gathered+scaled Xc in f16
    hipLaunchKernelGGL(k_scale2, dim3(2048), dim3(256), 0, stream,
                       x, cinv, xs, xs_h, (long long)Bn * n / 4);
    hipLaunchKernelGGL(k_gather_cvt, dim3(m), dim3(256), 0, stream,
                       X_data, midx, cinv, Xc_h, n);

    // 3) weights -> f16
    hipLaunchKernelGGL(k_cvt, dim3(256), dim3(256), 0, stream, W_q, Wq_h, (long long)a * n / 4, 1.f);
    hipLaunchKernelGGL(k_cvt, dim3(256), dim3(256), 0, stream, W_k, Wk_h, (long long)a * n / 4, 1.f);
    hipLaunchKernelGGL(k_cvt, dim3(1024), dim3(256), 0, stream, W_v, Wv_h, (long long)n * n / 4, 1.f);

    // 4) projections: q,k on 128² m97 kernel; v on the 256² pipelined kernel
    hipLaunchKernelGGL(k_gemm4, dim3(Bn / 128, a / 128), dim3(256), 0, stream,
                       xs_h, n, Wq_h, n, qmat, a, n, (float*)nullptr, 0ll);
    hipLaunchKernelGGL(k_gemm4, dim3(m / 128, a / 128), dim3(256), 0, stream,
                       Xc_h, n, Wk_h, n, kmat, a, n, (float*)nullptr, 0ll);
    hipLaunchKernelGGL((k_g256<0>), dim3(m / 256, n / 256), dim3(512), 0, stream,
                       Xc_h, n, Wv_h, n, vout, n, n, (float*)nullptr, 0ll);

    // 5) LayerNorms (f32); f16 copies: q scaled by 1/sqrt(a), k plain, v transposed
    float sc = 1.0f / sqrtf((float)a);
    hipLaunchKernelGGL(k_layernorm<1>, dim3(Bn), dim3(256), 0, stream, qmat, g_q, b_q, a);
    hipLaunchKernelGGL(k_layernorm<1>, dim3(m),  dim3(256), 0, stream, kmat, g_k, b_k, a);
    hipLaunchKernelGGL(k_layernorm<4>, dim3(m),  dim3(256), 0, stream, vout, g_v, b_v, n);
    hipLaunchKernelGGL(k_cvt, dim3(1024), dim3(256), 0, stream, qmat, q_h, (long long)Bn * a / 4, sc);
    hipLaunchKernelGGL(k_cvt, dim3(4096), dim3(256), 0, stream, kmat, k_h, (long long)m * a / 4, 1.f);
    hipLaunchKernelGGL(k_tcvt, dim3(n / 32, m / 32), dim3(256), 0, stream, vout, vT_h, m, n);

    long long zstride = (long long)Bn * n;
    if (attn_h) {
        // 6) S (pre-scaled, f16) -> attn_h; softmax reads f16, writes f32 + f16
        hipLaunchKernelGGL((k_g256<1>), dim3(Bn / 256, m / 256), dim3(512), 0, stream,
                           q_h, a, k_h, a, attn_h, m, a, (float*)nullptr, 0ll);
        hipLaunchKernelGGL(k_softmax_h, dim3(Bn), dim3(256), 0, stream, attn_h, attn);
        // 7) x_hat = attn @ v, split-K=4 into aliased partials, then reduce
        hipLaunchKernelGGL((k_g256<0>), dim3(Bn / 256, n / 256, SK), dim3(512), 0, stream,
                           attn_h, m, vT_h, m, xhat, n, m, splitk, zstride);
        hipLaunchKernelGGL(k_redux, dim3(2048), dim3(256), 0, stream,
                           splitk, xhat, (long long)Bn * n / 4, zstride / 4, SK);
    } else {
        // fallback (never taken so far): f32 logits + legacy softmax; x_hat
        // via f32->f16 cvt of attn into vT-sized spare is not available, so
        // reuse q/k buffers region is unsafe -> do logits f32 + softmax only,
        // then cvt attn into kmat-region (16 MB too small) is impossible:
        // instead run x_hat from f16 copy written over Xc_h (32 MB = exactly
        // Bn*m/4? no). Pragmatically: this path has never triggered; keep
        // the legacy correct-but-slower route via k_gemm4 on f32 A.
        hipLaunchKernelGGL((k_g256<0>), dim3(Bn / 256, m / 256), dim3(512), 0, stream,
                           q_h, a, k_h, a, attn, m, a, (float*)nullptr, 0ll);
        hipLaunchKernelGGL(k_softmax, dim3(Bn), dim3(256), 0, stream, attn, (  _Float16*)nullptr, 1.0f);
        // cvt attn (f32) to f16 in-place-capable buffer: reuse Xc_h (m*n*2 =
        // 32MB) is too small for Bn*m*2 (128MB) -> fall back to direct f32-A
        // GEMM path is unavailable; as a last resort reuse splitk region for
        // a chunked cvt+GEMM. Given this path has never been exercised, emit
        // a defensive chunked loop: process Bn in 4 chunks of 1024 rows,
        // cvt chunk into (  _Float16*)splitk then GEMM chunk.
        _Float16* chunk_h = (_Float16*)splitk;           // 1024*16384*2 = 32MB
        for (int cb = 0; cb < 4; ++cb) {
            const float* src = attn + (long long)cb * 1024 * m;
            hipLaunchKernelGGL(k_cvt, dim3(4096), dim3(256), 0, stream,
                               src, chunk_h, (long long)1024 * m / 4, 1.f);
            hipLaunchKernelGGL((k_g256<0>), dim3(1024 / 256, n / 256), dim3(512), 0, stream,
                               chunk_h, m, vT_h, m, xhat + (long long)cb * 1024 * n, n, m,
                               (float*)nullptr, 0ll);
        }
    }
}